// Round 1
// baseline (307.701 us; speedup 1.0000x reference)
//
#include <hip/hip_runtime.h>

// PETP_Quadratic: y = sum_t fctp(x_t, x_t, W_t), t in {self, flavor, nunubar, all}
// Strategy: pair-feature GEMM in fp16 MFMA (16x16x32), fp32 accumulate.
//   y_s[p,w]   = sum_uv [ s s^T ]  . norm*W0[u,v,w]  +  [Gram(v)] . norm*inv_sqrt3*W1[u,v,w]
//   y_v[p,w,k] = sum_uv [ s[u] v[v,k] ] . norm*(W2[u,v,w] + W3[v,u,w])
// Prep kernel folds scales + W3-transpose into f16 weight mats in d_ws.

typedef _Float16 half8 __attribute__((ext_vector_type(8)));
typedef float   float4_t __attribute__((ext_vector_type(4)));

#define NORM 0.022097086912079608f   /* 1/(32*sqrt(2)) */
#define INV_SQRT3 0.5773502691896258f

// ---------------- prep: build folded f16 weights in workspace ----------------
// B1[t][n=w][k], k in [0,2048): k = seg*1024 + u*32 + v
//   seg0: NORM * W_t[0][u][v][w]
//   seg1: NORM*INV_SQRT3 * W_t[1][u][v][w]
// B2[t][n=w][k], k in [0,1024): k = u*32 + v
//   NORM * (W_t[2][u][v][w] + W_t[3][v][u][w])
__global__ void prep_kernel(const float* __restrict__ Wa, const float* __restrict__ Wb,
                            const float* __restrict__ Wc, const float* __restrict__ Wd,
                            _Float16* __restrict__ B1, _Float16* __restrict__ B2) {
    const float* Ws[4] = {Wa, Wb, Wc, Wd};
    int idx = blockIdx.x * 256 + threadIdx.x;
    if (idx < 4 * 32 * 2048) {
        int t = idx >> 16;            // 32*2048 per variant
        int n = (idx >> 11) & 31;
        int k = idx & 2047;
        int seg = k >> 10;
        int u = (k >> 5) & 31;
        int v = k & 31;
        const float* W = Ws[t];
        float val;
        if (seg == 0) val = NORM * W[0 * 32768 + u * 1024 + v * 32 + n];
        else          val = NORM * INV_SQRT3 * W[1 * 32768 + u * 1024 + v * 32 + n];
        B1[idx] = (_Float16)val;      // idx == (t*32+n)*2048 + k
    } else {
        int idx2 = idx - 4 * 32 * 2048;
        if (idx2 < 4 * 32 * 1024) {
            int t = idx2 >> 15;       // 32*1024 per variant
            int n = (idx2 >> 10) & 31;
            int k = idx2 & 1023;
            int u = k >> 5;
            int v = k & 31;
            const float* W = Ws[t];
            float val = NORM * (W[2 * 32768 + u * 1024 + v * 32 + n] +
                                W[3 * 32768 + v * 1024 + u * 32 + n]);
            B2[idx2] = (_Float16)val; // idx2 == (t*32+n)*1024 + k
        }
    }
}

// ---------------- main kernel ----------------
// Grid: nbatch/32 WGs of 256 threads (4 waves). WG owns 32 batches = 192 positions.
// Wave owns 48 positions: 3 ys-tiles (16 pos) and 9 yv-tiles (16 (p,k)-rows, k-major).
__launch_bounds__(256, 2)
__global__ void petp_main(const float* __restrict__ x,
                          const _Float16* __restrict__ B1,
                          const _Float16* __restrict__ B2,
                          float* __restrict__ y) {
    __shared__ _Float16 feat_s[192 * 32];   // [posL][ch]          12 KB
    __shared__ _Float16 feat_v[192 * 96];   // [posL][i(0..2)][u]  36 KB
    __shared__ _Float16 b1c[32 * 136];      // [n][128 + 8 pad]    8.5 KB
    __shared__ _Float16 b2c[32 * 72];       // [n][64 + 8 pad]     4.5 KB

    const int tid  = threadIdx.x;
    const int wave = tid >> 6;
    const int lane = tid & 63;
    const int m = lane & 15;   // M row within 16-tile / B column n
    const int q = lane >> 4;   // quad -> k-slice q*8 .. q*8+7
    const int wg = blockIdx.x;
    const int pbase = wave * 48;

    float4_t acc_s[3][2];      // [ys tile][n-half]
    float4_t acc_v[9][2];      // [yv tile][n-half]
    float4_t zero = {0.f, 0.f, 0.f, 0.f};
#pragma unroll
    for (int i = 0; i < 3; ++i) { acc_s[i][0] = zero; acc_s[i][1] = zero; }
#pragma unroll
    for (int i = 0; i < 9; ++i) { acc_v[i][0] = zero; acc_v[i][1] = zero; }

    const float* xg = x + (size_t)wg * (192 * 128);

#pragma unroll 1
    for (int t = 0; t < 4; ++t) {
        __syncthreads();   // prior reads of feat_* done
        // ---- build variant-t features into LDS ----
#pragma unroll 1
        for (int it = 0; it < 16; ++it) {
            int item = it * 256 + tid;       // 32 batches x 128 channels
            int b = item >> 7;
            int c = item & 127;
            const float* bp = xg + b * 768 + c;
            float v00 = bp[0],   v01 = bp[128], v02 = bp[256];
            float v10 = bp[384], v11 = bp[512], v12 = bp[640];
            float rs0 = v00 + v01 + v02, rs1 = v10 + v11 + v12;
            float cs0 = v00 + v10, cs1 = v01 + v11, cs2 = v02 + v12;
            float tot = rs0 + rs1;
            float xv[6] = {v00, v01, v02, v10, v11, v12};
            float rs[2] = {rs0, rs1};
            float cs[3] = {cs0, cs1, cs2};
#pragma unroll
            for (int p6 = 0; p6 < 6; ++p6) {
                int i = p6 / 3, j = p6 % 3;
                float xvv = xv[p6];
                float f;
                if      (t == 0) f = xvv;
                else if (t == 1) f = (rs[i] - xvv) * 0.5f;
                else if (t == 2) f = cs[j] - xvv;
                else             f = (tot - rs[i] - cs[j] + xvv) * 0.5f;
                int posL = b * 6 + p6;
                _Float16 h = (_Float16)f;
                if (c < 32) {
                    feat_s[posL * 32 + c] = h;
                } else {
                    int cc = c - 32;                 // channel = 32 + u*3 + i
                    feat_v[posL * 96 + (cc % 3) * 32 + (cc / 3)] = h;
                }
            }
        }
        __syncthreads();

        // ---- persistent per-lane A-side slices (k-invariant) ----
        half8 p_ss[3];        // s[pos][q*8..q*8+7] per ys tile
        half8 p_v[3][3];      // v[pos][i][q*8..+7]: gram (all i) + yv (per component)
#pragma unroll
        for (int tl = 0; tl < 3; ++tl) {
            int posL = pbase + tl * 16 + m;
            p_ss[tl] = *(const half8*)&feat_s[posL * 32 + q * 8];
#pragma unroll
            for (int i = 0; i < 3; ++i)
                p_v[tl][i] = *(const half8*)&feat_v[posL * 96 + i * 32 + q * 8];
        }

        const _Float16* B1t = B1 + t * (32 * 2048);
        const _Float16* B2t = B2 + t * (32 * 1024);

#pragma unroll 1
        for (int ch = 0; ch < 16; ++ch) {
            __syncthreads();   // previous chunk consumed
            // stage B1 chunk (32 rows x 128 k) and B2 chunk (32 x 64)
#pragma unroll
            for (int p = 0; p < 2; ++p) {
                int idx = p * 256 + tid;
                int r = idx >> 4, c16 = idx & 15;
                *(uint4*)&b1c[r * 136 + c16 * 8] =
                    *(const uint4*)&B1t[r * 2048 + ch * 128 + c16 * 8];
            }
            {
                int r = tid >> 3, c16 = tid & 7;
                *(uint4*)&b2c[r * 72 + c16 * 8] =
                    *(const uint4*)&B2t[r * 1024 + ch * 64 + c16 * 8];
            }
            __syncthreads();

            const bool gram = (ch >= 8);
            // ---- ys part: 4 u-steps over 128 B1 rows ----
#pragma unroll
            for (int s = 0; s < 4; ++s) {
                int u = (ch & 7) * 4 + s;
                half8 bf0 = *(const half8*)&b1c[m * 136 + s * 32 + q * 8];
                half8 bf1 = *(const half8*)&b1c[(16 + m) * 136 + s * 32 + q * 8];
#pragma unroll
                for (int tl = 0; tl < 3; ++tl) {
                    int posL = pbase + tl * 16 + m;
                    half8 af;
                    if (!gram) {
                        _Float16 bc = feat_s[posL * 32 + u];
                        af = p_ss[tl] * bc;
                    } else {
                        _Float16 b0 = feat_v[posL * 96 + 0 * 32 + u];
                        _Float16 b1 = feat_v[posL * 96 + 1 * 32 + u];
                        _Float16 b2 = feat_v[posL * 96 + 2 * 32 + u];
                        af = p_v[tl][0] * b0 + p_v[tl][1] * b1 + p_v[tl][2] * b2;
                    }
                    acc_s[tl][0] = __builtin_amdgcn_mfma_f32_16x16x32_f16(af, bf0, acc_s[tl][0], 0, 0, 0);
                    acc_s[tl][1] = __builtin_amdgcn_mfma_f32_16x16x32_f16(af, bf1, acc_s[tl][1], 0, 0, 0);
                }
            }
            // ---- yv part: 2 u-steps over 64 B2 rows ----
#pragma unroll
            for (int s2 = 0; s2 < 2; ++s2) {
                int u = ch * 2 + s2;
                half8 bf0 = *(const half8*)&b2c[m * 72 + s2 * 32 + q * 8];
                half8 bf1 = *(const half8*)&b2c[(16 + m) * 72 + s2 * 32 + q * 8];
#pragma unroll
                for (int tv = 0; tv < 9; ++tv) {
                    int sub = tv % 3, kc = tv / 3;
                    int posL = pbase + sub * 16 + m;
                    _Float16 bc = feat_s[posL * 32 + u];
                    half8 af = p_v[sub][kc] * bc;
                    acc_v[tv][0] = __builtin_amdgcn_mfma_f32_16x16x32_f16(af, bf0, acc_v[tv][0], 0, 0, 0);
                    acc_v[tv][1] = __builtin_amdgcn_mfma_f32_16x16x32_f16(af, bf1, acc_v[tv][1], 0, 0, 0);
                }
            }
        }
    }

    // ---- epilogue: C/D layout col(n)=lane&15, row(m)=(lane>>4)*4+reg ----
    float* yg = y + (size_t)wg * (192 * 128);
#pragma unroll
    for (int tl = 0; tl < 3; ++tl) {
#pragma unroll
        for (int nh = 0; nh < 2; ++nh) {
            int w = nh * 16 + m;
#pragma unroll
            for (int r = 0; r < 4; ++r) {
                int pos = wave * 48 + tl * 16 + q * 4 + r;
                yg[pos * 128 + w] = acc_s[tl][nh][r];
            }
        }
    }
#pragma unroll
    for (int tv = 0; tv < 9; ++tv) {
        int sub = tv % 3, kc = tv / 3;
#pragma unroll
        for (int nh = 0; nh < 2; ++nh) {
            int w = nh * 16 + m;
#pragma unroll
            for (int r = 0; r < 4; ++r) {
                int pos = wave * 48 + sub * 16 + q * 4 + r;
                yg[pos * 128 + 32 + 3 * w + kc] = acc_v[tv][nh][r];
            }
        }
    }
}

extern "C" void kernel_launch(void* const* d_in, const int* in_sizes, int n_in,
                              void* d_out, int out_size, void* d_ws, size_t ws_size,
                              hipStream_t stream) {
    const float* x  = (const float*)d_in[0];
    const float* Wa = (const float*)d_in[1];   // W_self
    const float* Wb = (const float*)d_in[2];   // W_flavor
    const float* Wc = (const float*)d_in[3];   // W_nunubar
    const float* Wd = (const float*)d_in[4];   // W_all
    float* y = (float*)d_out;

    _Float16* B1 = (_Float16*)d_ws;            // 4*32*2048 f16 = 512 KB
    _Float16* B2 = B1 + 4 * 32 * 2048;         // 4*32*1024 f16 = 256 KB

    int nbatch = in_sizes[0] / 768;            // 16384
    int nwg = nbatch / 32;                     // 512

    prep_kernel<<<(4 * 32 * 2048 + 4 * 32 * 1024) / 256, 256, 0, stream>>>(Wa, Wb, Wc, Wd, B1, B2);
    petp_main<<<nwg, 256, 0, stream>>>(x, B1, B2, y);
}

// Round 2
// 292.024 us; speedup vs baseline: 1.0537x; 1.0537x over previous
//
#include <hip/hip_runtime.h>

// PETP_Quadratic: y = sum_t fctp(x_t, x_t, W_t), t in {self, flavor, nunubar, all}
// Pair-feature GEMM in fp16 MFMA (16x16x32), fp32 accumulate.
//   y_s[p,w]   = [s s^T].norm*W0  +  [Gram(v)].norm*inv_sqrt3*W1
//   y_v[p,w,k] = [s[u] v[v,k]].norm*(W2[u,v,w] + W3[v,u,w])
// R2: featT transposed in LDS (conflict-free broadcasts), B read from global
// (L2-resident, no ch-loop barriers).

typedef _Float16 half8 __attribute__((ext_vector_type(8)));
typedef float   float4_t __attribute__((ext_vector_type(4)));

#define NORM 0.022097086912079608f   /* 1/(32*sqrt(2)) */
#define INV_SQRT3 0.5773502691896258f
#define FS 194                        /* featT row stride (halfwords), odd word count */

// ---------------- prep: build folded f16 weights in workspace ----------------
__global__ void prep_kernel(const float* __restrict__ Wa, const float* __restrict__ Wb,
                            const float* __restrict__ Wc, const float* __restrict__ Wd,
                            _Float16* __restrict__ B1, _Float16* __restrict__ B2) {
    const float* Ws[4] = {Wa, Wb, Wc, Wd};
    int idx = blockIdx.x * 256 + threadIdx.x;
    if (idx < 4 * 32 * 2048) {
        int t = idx >> 16;
        int n = (idx >> 11) & 31;
        int k = idx & 2047;
        int seg = k >> 10;
        int u = (k >> 5) & 31;
        int v = k & 31;
        const float* W = Ws[t];
        float val;
        if (seg == 0) val = NORM * W[0 * 32768 + u * 1024 + v * 32 + n];
        else          val = NORM * INV_SQRT3 * W[1 * 32768 + u * 1024 + v * 32 + n];
        B1[idx] = (_Float16)val;
    } else {
        int idx2 = idx - 4 * 32 * 2048;
        if (idx2 < 4 * 32 * 1024) {
            int t = idx2 >> 15;
            int n = (idx2 >> 10) & 31;
            int k = idx2 & 1023;
            int u = k >> 5;
            int v = k & 31;
            const float* W = Ws[t];
            float val = NORM * (W[2 * 32768 + u * 1024 + v * 32 + n] +
                                W[3 * 32768 + v * 1024 + u * 32 + n]);
            B2[idx2] = (_Float16)val;
        }
    }
}

// ---------------- main kernel ----------------
// WG = 256 thr (4 waves) owns 32 batches = 192 positions; wave owns 48.
// featT[row][pos]: rows 0..31 = s-channel u; rows 32+i*32+u = v-component i, channel u.
__launch_bounds__(256, 2)
__global__ void petp_main(const float* __restrict__ x,
                          const _Float16* __restrict__ B1,
                          const _Float16* __restrict__ B2,
                          float* __restrict__ y) {
    __shared__ _Float16 featT[128 * FS];   // 49664 B

    const int tid  = threadIdx.x;
    const int wave = tid >> 6;
    const int lane = tid & 63;
    const int m = lane & 15;   // M row within 16-tile / B column n
    const int q = lane >> 4;   // quad -> k-slice q*8..q*8+7
    const int wg = blockIdx.x;
    const int pbase = wave * 48;

    float4_t acc_s[3][2];
    float4_t acc_v[9][2];
    float4_t zero = {0.f, 0.f, 0.f, 0.f};
#pragma unroll
    for (int i = 0; i < 3; ++i) { acc_s[i][0] = zero; acc_s[i][1] = zero; }
#pragma unroll
    for (int i = 0; i < 9; ++i) { acc_v[i][0] = zero; acc_v[i][1] = zero; }

    const float* xg = x + (size_t)wg * (192 * 128);

#pragma unroll 1
    for (int t = 0; t < 4; ++t) {
        __syncthreads();   // prior variant's readers done
        // ---- build variant-t features into transposed LDS ----
#pragma unroll 1
        for (int it = 0; it < 16; ++it) {
            int item = it * 256 + tid;       // 32 batches x 128 channels
            int b = item >> 7;
            int c = item & 127;
            const float* bp = xg + b * 768 + c;
            float v00 = bp[0],   v01 = bp[128], v02 = bp[256];
            float v10 = bp[384], v11 = bp[512], v12 = bp[640];
            float rs0 = v00 + v01 + v02, rs1 = v10 + v11 + v12;
            float cs0 = v00 + v10, cs1 = v01 + v11, cs2 = v02 + v12;
            float tot = rs0 + rs1;
            float xv[6] = {v00, v01, v02, v10, v11, v12};
            float rs[2] = {rs0, rs1};
            float cs[3] = {cs0, cs1, cs2};
            int row;
            if (c < 32) row = c;
            else { int cc = c - 32; row = 32 + (cc % 3) * 32 + (cc / 3); }
#pragma unroll
            for (int p6 = 0; p6 < 6; ++p6) {
                int i = p6 / 3, j = p6 % 3;
                float xvv = xv[p6];
                float f;
                if      (t == 0) f = xvv;
                else if (t == 1) f = (rs[i] - xvv) * 0.5f;
                else if (t == 2) f = cs[j] - xvv;
                else             f = (tot - rs[i] - cs[j] + xvv) * 0.5f;
                int posL = b * 6 + p6;
                featT[row * FS + posL] = (_Float16)f;
            }
        }
        __syncthreads();

        // ---- persistent per-lane A-side slices (k-invariant), column reads ----
        half8 p_ss[3];
        half8 p_v[3][3];
#pragma unroll
        for (int tl = 0; tl < 3; ++tl) {
            int posL = pbase + tl * 16 + m;
#pragma unroll
            for (int j = 0; j < 8; ++j)
                p_ss[tl][j] = featT[(q * 8 + j) * FS + posL];
#pragma unroll
            for (int i = 0; i < 3; ++i)
#pragma unroll
                for (int j = 0; j < 8; ++j)
                    p_v[tl][i][j] = featT[(32 + i * 32 + q * 8 + j) * FS + posL];
        }

        const _Float16* B1t = B1 + t * (32 * 2048);
        const _Float16* B2t = B2 + t * (32 * 1024);
        const _Float16* b1r0 = B1t + m * 2048 + q * 8;
        const _Float16* b1r1 = B1t + (16 + m) * 2048 + q * 8;
        const _Float16* b2r0 = B2t + m * 1024 + q * 8;
        const _Float16* b2r1 = B2t + (16 + m) * 1024 + q * 8;

#pragma unroll 1
        for (int ch = 0; ch < 16; ++ch) {
            // B fragments straight from global (L1/L2-resident, no barriers)
            half8 b1f[2][4];
            half8 b2f[2][2];
#pragma unroll
            for (int s = 0; s < 4; ++s) {
                b1f[0][s] = *(const half8*)(b1r0 + ch * 128 + s * 32);
                b1f[1][s] = *(const half8*)(b1r1 + ch * 128 + s * 32);
            }
#pragma unroll
            for (int s2 = 0; s2 < 2; ++s2) {
                b2f[0][s2] = *(const half8*)(b2r0 + ch * 64 + s2 * 32);
                b2f[1][s2] = *(const half8*)(b2r1 + ch * 64 + s2 * 32);
            }

            if (ch < 8) {
                // ---- ys: s.s^T pair features ----
#pragma unroll
                for (int s = 0; s < 4; ++s) {
                    int u = ch * 4 + s;
#pragma unroll
                    for (int tl = 0; tl < 3; ++tl) {
                        int posL = pbase + tl * 16 + m;
                        _Float16 bc = featT[u * FS + posL];
                        half8 af = p_ss[tl] * bc;
                        acc_s[tl][0] = __builtin_amdgcn_mfma_f32_16x16x32_f16(af, b1f[0][s], acc_s[tl][0], 0, 0, 0);
                        acc_s[tl][1] = __builtin_amdgcn_mfma_f32_16x16x32_f16(af, b1f[1][s], acc_s[tl][1], 0, 0, 0);
                    }
                }
            } else {
                // ---- ys: Gram(v) pair features ----
#pragma unroll
                for (int s = 0; s < 4; ++s) {
                    int u = (ch - 8) * 4 + s;
#pragma unroll
                    for (int tl = 0; tl < 3; ++tl) {
                        int posL = pbase + tl * 16 + m;
                        _Float16 g0 = featT[(32 + u) * FS + posL];
                        _Float16 g1 = featT[(64 + u) * FS + posL];
                        _Float16 g2 = featT[(96 + u) * FS + posL];
                        half8 af = p_v[tl][0] * g0 + p_v[tl][1] * g1 + p_v[tl][2] * g2;
                        acc_s[tl][0] = __builtin_amdgcn_mfma_f32_16x16x32_f16(af, b1f[0][s], acc_s[tl][0], 0, 0, 0);
                        acc_s[tl][1] = __builtin_amdgcn_mfma_f32_16x16x32_f16(af, b1f[1][s], acc_s[tl][1], 0, 0, 0);
                    }
                }
            }
            // ---- yv: s[u] v[v,k] pair features ----
#pragma unroll
            for (int s2 = 0; s2 < 2; ++s2) {
                int u = ch * 2 + s2;
                _Float16 bcs[3];
#pragma unroll
                for (int sub = 0; sub < 3; ++sub)
                    bcs[sub] = featT[u * FS + pbase + sub * 16 + m];
#pragma unroll
                for (int tv = 0; tv < 9; ++tv) {
                    int sub = tv % 3, kc = tv / 3;
                    half8 af = p_v[sub][kc] * bcs[sub];
                    acc_v[tv][0] = __builtin_amdgcn_mfma_f32_16x16x32_f16(af, b2f[0][s2], acc_v[tv][0], 0, 0, 0);
                    acc_v[tv][1] = __builtin_amdgcn_mfma_f32_16x16x32_f16(af, b2f[1][s2], acc_v[tv][1], 0, 0, 0);
                }
            }
        }
    }

    // ---- epilogue: C/D layout col(n)=lane&15, row=(lane>>4)*4+reg ----
    float* yg = y + (size_t)wg * (192 * 128);
#pragma unroll
    for (int tl = 0; tl < 3; ++tl) {
#pragma unroll
        for (int nh = 0; nh < 2; ++nh) {
            int w = nh * 16 + m;
#pragma unroll
            for (int r = 0; r < 4; ++r) {
                int pos = wave * 48 + tl * 16 + q * 4 + r;
                yg[pos * 128 + w] = acc_s[tl][nh][r];
            }
        }
    }
#pragma unroll
    for (int tv = 0; tv < 9; ++tv) {
        int sub = tv % 3, kc = tv / 3;
#pragma unroll
        for (int nh = 0; nh < 2; ++nh) {
            int w = nh * 16 + m;
#pragma unroll
            for (int r = 0; r < 4; ++r) {
                int pos = wave * 48 + sub * 16 + q * 4 + r;
                yg[pos * 128 + 32 + 3 * w + kc] = acc_v[tv][nh][r];
            }
        }
    }
}

extern "C" void kernel_launch(void* const* d_in, const int* in_sizes, int n_in,
                              void* d_out, int out_size, void* d_ws, size_t ws_size,
                              hipStream_t stream) {
    const float* x  = (const float*)d_in[0];
    const float* Wa = (const float*)d_in[1];
    const float* Wb = (const float*)d_in[2];
    const float* Wc = (const float*)d_in[3];
    const float* Wd = (const float*)d_in[4];
    float* y = (float*)d_out;

    _Float16* B1 = (_Float16*)d_ws;            // 4*32*2048 f16 = 512 KB
    _Float16* B2 = B1 + 4 * 32 * 2048;         // 4*32*1024 f16 = 256 KB

    int nbatch = in_sizes[0] / 768;            // 16384
    int nwg = nbatch / 32;                     // 512

    prep_kernel<<<(4 * 32 * 2048 + 4 * 32 * 1024) / 256, 256, 0, stream>>>(Wa, Wb, Wc, Wd, B1, B2);
    petp_main<<<nwg, 256, 0, stream>>>(x, B1, B2, y);
}

// Round 3
// 228.534 us; speedup vs baseline: 1.3464x; 1.2778x over previous
//
#include <hip/hip_runtime.h>

// PETP_Quadratic: y = sum_t fctp(x_t, x_t, W_t), t in {self, flavor, nunubar, all}
// Pair-feature GEMM in fp16 MFMA (16x16x32), fp32 accumulate.
//   y_s[p,w]   = [s s^T].norm*W0  +  [Gram(v)].norm*inv_sqrt3*W1
//   y_v[p,w,k] = [s[u] v[v,k]].norm*(W2[u,v,w] + W3[v,u,w])
// R3: B pre-swizzled into MFMA-fragment order (1KB contiguous per fragment,
// lane-coalesced, L1-resident). featT transposed in LDS (conflict-free).

typedef _Float16 half8 __attribute__((ext_vector_type(8)));
typedef float   float4_t __attribute__((ext_vector_type(4)));

#define NORM 0.022097086912079608f   /* 1/(32*sqrt(2)) */
#define INV_SQRT3 0.5773502691896258f
#define FS 194                        /* featT row stride (halfwords), odd word count */

// ---------------- prep: build folded, fragment-swizzled f16 weights ----------------
// B1s: 4*16*4*2 blocks of 512 half (1KB). Block bi = ((t*16+ch)*4+s)*2+h.
//   element [lane*8+j]: lane = q*16+m -> n = h*16+m, k = ch*128+s*32+q*8+j
//   k = seg*1024+u*32+v: seg0 = NORM*W[0][u][v][n], seg1 = NORM*ISQ3*W[1][u][v][n]
// B2s: 4*16*2*2 blocks of 512 half. bi2 = ((t*16+ch)*2+s2)*2+h.
//   k = ch*64+s2*32+q*8+j = u*32+v: NORM*(W[2][u][v][n]+W[3][v][u][n])
__global__ void prep_kernel(const float* __restrict__ Wa, const float* __restrict__ Wb,
                            const float* __restrict__ Wc, const float* __restrict__ Wd,
                            _Float16* __restrict__ B1s, _Float16* __restrict__ B2s) {
    const float* Ws[4] = {Wa, Wb, Wc, Wd};
    int idx = blockIdx.x * 256 + threadIdx.x;
    if (idx < 262144) {
        int j    = idx & 7;
        int lane = (idx >> 3) & 63;
        int h    = (idx >> 9) & 1;
        int s    = (idx >> 10) & 3;
        int ch   = (idx >> 12) & 15;
        int t    = idx >> 16;
        int m = lane & 15, q = lane >> 4;
        int n = h * 16 + m;
        int k = ch * 128 + s * 32 + q * 8 + j;
        int seg = k >> 10, u = (k >> 5) & 31, v = k & 31;
        const float* W = Ws[t];
        float val;
        if (seg == 0) val = NORM * W[0 * 32768 + u * 1024 + v * 32 + n];
        else          val = NORM * INV_SQRT3 * W[1 * 32768 + u * 1024 + v * 32 + n];
        B1s[idx] = (_Float16)val;
    } else {
        int idx2 = idx - 262144;
        if (idx2 < 131072) {
            int j    = idx2 & 7;
            int lane = (idx2 >> 3) & 63;
            int h    = (idx2 >> 9) & 1;
            int s2   = (idx2 >> 10) & 1;
            int ch   = (idx2 >> 11) & 15;
            int t    = idx2 >> 15;
            int m = lane & 15, q = lane >> 4;
            int n = h * 16 + m;
            int k = ch * 64 + s2 * 32 + q * 8 + j;
            int u = k >> 5, v = k & 31;
            const float* W = Ws[t];
            float val = NORM * (W[2 * 32768 + u * 1024 + v * 32 + n] +
                                W[3 * 32768 + v * 1024 + u * 32 + n]);
            B2s[idx2] = (_Float16)val;
        }
    }
}

// ---------------- main kernel ----------------
// WG = 256 thr (4 waves) owns 32 batches = 192 positions; wave owns 48.
// featT[row][pos]: rows 0..31 = s-channel u; rows 32+i*32+u = v-component i, channel u.
__launch_bounds__(256, 2)
__global__ void petp_main(const float* __restrict__ x,
                          const _Float16* __restrict__ B1s,
                          const _Float16* __restrict__ B2s,
                          float* __restrict__ y) {
    __shared__ _Float16 featT[128 * FS];   // 49664 B

    const int tid  = threadIdx.x;
    const int wave = tid >> 6;
    const int lane = tid & 63;
    const int m = lane & 15;   // M row within 16-tile / B column n
    const int q = lane >> 4;   // quad -> k-slice q*8..q*8+7
    const int wg = blockIdx.x;
    const int pbase = wave * 48;

    float4_t acc_s[3][2];
    float4_t acc_v[9][2];
    float4_t zero = {0.f, 0.f, 0.f, 0.f};
#pragma unroll
    for (int i = 0; i < 3; ++i) { acc_s[i][0] = zero; acc_s[i][1] = zero; }
#pragma unroll
    for (int i = 0; i < 9; ++i) { acc_v[i][0] = zero; acc_v[i][1] = zero; }

    const float* xg = x + (size_t)wg * (192 * 128);

#pragma unroll 1
    for (int t = 0; t < 4; ++t) {
        __syncthreads();   // prior variant's readers done
        // ---- build variant-t features into transposed LDS ----
#pragma unroll 1
        for (int it = 0; it < 16; ++it) {
            int item = it * 256 + tid;       // 32 batches x 128 channels
            int b = item >> 7;
            int c = item & 127;
            const float* bp = xg + b * 768 + c;
            float v00 = bp[0],   v01 = bp[128], v02 = bp[256];
            float v10 = bp[384], v11 = bp[512], v12 = bp[640];
            float rs0 = v00 + v01 + v02, rs1 = v10 + v11 + v12;
            float cs0 = v00 + v10, cs1 = v01 + v11, cs2 = v02 + v12;
            float tot = rs0 + rs1;
            float xv[6] = {v00, v01, v02, v10, v11, v12};
            float rs[2] = {rs0, rs1};
            float cs[3] = {cs0, cs1, cs2};
            int row;
            if (c < 32) row = c;
            else { int cc = c - 32; row = 32 + (cc % 3) * 32 + (cc / 3); }
#pragma unroll
            for (int p6 = 0; p6 < 6; ++p6) {
                int i = p6 / 3, j = p6 % 3;
                float xvv = xv[p6];
                float f;
                if      (t == 0) f = xvv;
                else if (t == 1) f = (rs[i] - xvv) * 0.5f;
                else if (t == 2) f = cs[j] - xvv;
                else             f = (tot - rs[i] - cs[j] + xvv) * 0.5f;
                int posL = b * 6 + p6;
                featT[row * FS + posL] = (_Float16)f;
            }
        }
        __syncthreads();

        // ---- persistent per-lane A-side slices (k-invariant), column reads ----
        half8 p_ss[3];
        half8 p_v[3][3];
#pragma unroll
        for (int tl = 0; tl < 3; ++tl) {
            int posL = pbase + tl * 16 + m;
#pragma unroll
            for (int j = 0; j < 8; ++j)
                p_ss[tl][j] = featT[(q * 8 + j) * FS + posL];
#pragma unroll
            for (int i = 0; i < 3; ++i)
#pragma unroll
                for (int j = 0; j < 8; ++j)
                    p_v[tl][i][j] = featT[(32 + i * 32 + q * 8 + j) * FS + posL];
        }

        // fragment-swizzled B bases for this variant (lane-coalesced)
        const _Float16* B1w = B1s + t * 65536 + lane * 8;
        const _Float16* B2w = B2s + t * 32768 + lane * 8;

#pragma unroll 1
        for (int ch = 0; ch < 16; ++ch) {
            half8 b1f[2][4];
            half8 b2f[2][2];
#pragma unroll
            for (int s = 0; s < 4; ++s) {
                b1f[0][s] = *(const half8*)(B1w + ((ch * 4 + s) * 2 + 0) * 512);
                b1f[1][s] = *(const half8*)(B1w + ((ch * 4 + s) * 2 + 1) * 512);
            }
#pragma unroll
            for (int s2 = 0; s2 < 2; ++s2) {
                b2f[0][s2] = *(const half8*)(B2w + ((ch * 2 + s2) * 2 + 0) * 512);
                b2f[1][s2] = *(const half8*)(B2w + ((ch * 2 + s2) * 2 + 1) * 512);
            }

            if (ch < 8) {
                // ---- ys: s.s^T pair features ----
#pragma unroll
                for (int s = 0; s < 4; ++s) {
                    int u = ch * 4 + s;
#pragma unroll
                    for (int tl = 0; tl < 3; ++tl) {
                        int posL = pbase + tl * 16 + m;
                        _Float16 bc = featT[u * FS + posL];
                        half8 af = p_ss[tl] * bc;
                        acc_s[tl][0] = __builtin_amdgcn_mfma_f32_16x16x32_f16(af, b1f[0][s], acc_s[tl][0], 0, 0, 0);
                        acc_s[tl][1] = __builtin_amdgcn_mfma_f32_16x16x32_f16(af, b1f[1][s], acc_s[tl][1], 0, 0, 0);
                    }
                }
            } else {
                // ---- ys: Gram(v) pair features ----
#pragma unroll
                for (int s = 0; s < 4; ++s) {
                    int u = (ch - 8) * 4 + s;
#pragma unroll
                    for (int tl = 0; tl < 3; ++tl) {
                        int posL = pbase + tl * 16 + m;
                        _Float16 g0 = featT[(32 + u) * FS + posL];
                        _Float16 g1 = featT[(64 + u) * FS + posL];
                        _Float16 g2 = featT[(96 + u) * FS + posL];
                        half8 af = p_v[tl][0] * g0 + p_v[tl][1] * g1 + p_v[tl][2] * g2;
                        acc_s[tl][0] = __builtin_amdgcn_mfma_f32_16x16x32_f16(af, b1f[0][s], acc_s[tl][0], 0, 0, 0);
                        acc_s[tl][1] = __builtin_amdgcn_mfma_f32_16x16x32_f16(af, b1f[1][s], acc_s[tl][1], 0, 0, 0);
                    }
                }
            }
            // ---- yv: s[u] v[v,k] pair features ----
#pragma unroll
            for (int s2 = 0; s2 < 2; ++s2) {
                int u = ch * 2 + s2;
                _Float16 bcs[3];
#pragma unroll
                for (int sub = 0; sub < 3; ++sub)
                    bcs[sub] = featT[u * FS + pbase + sub * 16 + m];
#pragma unroll
                for (int tv = 0; tv < 9; ++tv) {
                    int sub = tv % 3, kc = tv / 3;
                    half8 af = p_v[sub][kc] * bcs[sub];
                    acc_v[tv][0] = __builtin_amdgcn_mfma_f32_16x16x32_f16(af, b2f[0][s2], acc_v[tv][0], 0, 0, 0);
                    acc_v[tv][1] = __builtin_amdgcn_mfma_f32_16x16x32_f16(af, b2f[1][s2], acc_v[tv][1], 0, 0, 0);
                }
            }
        }
    }

    // ---- epilogue: C/D layout col(n)=lane&15, row=(lane>>4)*4+reg ----
    float* yg = y + (size_t)wg * (192 * 128);
#pragma unroll
    for (int tl = 0; tl < 3; ++tl) {
#pragma unroll
        for (int nh = 0; nh < 2; ++nh) {
            int w = nh * 16 + m;
#pragma unroll
            for (int r = 0; r < 4; ++r) {
                int pos = wave * 48 + tl * 16 + q * 4 + r;
                yg[pos * 128 + w] = acc_s[tl][nh][r];
            }
        }
    }
#pragma unroll
    for (int tv = 0; tv < 9; ++tv) {
        int sub = tv % 3, kc = tv / 3;
#pragma unroll
        for (int nh = 0; nh < 2; ++nh) {
            int w = nh * 16 + m;
#pragma unroll
            for (int r = 0; r < 4; ++r) {
                int pos = wave * 48 + sub * 16 + q * 4 + r;
                yg[pos * 128 + 32 + 3 * w + kc] = acc_v[tv][nh][r];
            }
        }
    }
}

extern "C" void kernel_launch(void* const* d_in, const int* in_sizes, int n_in,
                              void* d_out, int out_size, void* d_ws, size_t ws_size,
                              hipStream_t stream) {
    const float* x  = (const float*)d_in[0];
    const float* Wa = (const float*)d_in[1];
    const float* Wb = (const float*)d_in[2];
    const float* Wc = (const float*)d_in[3];
    const float* Wd = (const float*)d_in[4];
    float* y = (float*)d_out;

    _Float16* B1s = (_Float16*)d_ws;           // 262144 half = 512 KB
    _Float16* B2s = B1s + 262144;              // 131072 half = 256 KB

    int nbatch = in_sizes[0] / 768;            // 16384
    int nwg = nbatch / 32;                     // 512

    prep_kernel<<<(262144 + 131072) / 256, 256, 0, stream>>>(Wa, Wb, Wc, Wd, B1s, B2s);
    petp_main<<<nwg, 256, 0, stream>>>(x, B1s, B2s, y);
}